// Round 2
// baseline (513.877 us; speedup 1.0000x reference)
//
#include <hip/hip_runtime.h>
#include <math.h>

#define EPSF 1e-12f
#define ATT_NORM_F 4.0f
#define H_DIM 8
#define C_DIM 16
#define N_NODES 100000

#define TPB 256
#define NBLK 1024
#define NTHREADS (NBLK * TPB)          // 262144
#define ITERS 31                        // ceil(8e6 / 262144) = 31

// ---------------------------------------------------------------------------
// Zero the seg table (N*H u32) plus the 2 barrier words right after it.
// ---------------------------------------------------------------------------
__global__ __launch_bounds__(256) void lip_zero(unsigned* __restrict__ p, int n)
{
    int i = blockIdx.x * 256 + threadIdx.x;
    if (i < n) p[i] = 0u;
}

// ---------------------------------------------------------------------------
// Device-scope grid barrier (all NBLK blocks co-resident by construction).
// count = bar[0] (zeroed each call), gen = bar[1] (zeroed each call).
// ---------------------------------------------------------------------------
__device__ __forceinline__ void grid_barrier(unsigned* bar, unsigned nblk)
{
    // __syncthreads lowers to s_waitcnt vmcnt(0) lgkmcnt(0) + s_barrier:
    // all this block's atomics/stores are complete (device-visible for
    // agent-scope atomics) before thread 0 announces arrival.
    __syncthreads();
    if (threadIdx.x == 0) {
        __threadfence();  // release: write back anything pending
        unsigned g = __hip_atomic_load(&bar[1], __ATOMIC_RELAXED,
                                       __HIP_MEMORY_SCOPE_AGENT);
        unsigned old = __hip_atomic_fetch_add(&bar[0], 1u, __ATOMIC_ACQ_REL,
                                              __HIP_MEMORY_SCOPE_AGENT);
        if (old == nblk - 1) {
            __hip_atomic_store(&bar[0], 0u, __ATOMIC_RELAXED,
                               __HIP_MEMORY_SCOPE_AGENT);
            __hip_atomic_fetch_add(&bar[1], 1u, __ATOMIC_RELEASE,
                                   __HIP_MEMORY_SCOPE_AGENT);
        } else {
            while (__hip_atomic_load(&bar[1], __ATOMIC_ACQUIRE,
                                     __HIP_MEMORY_SCOPE_AGENT) == g) {
                __builtin_amdgcn_s_sleep(2);
            }
        }
        __threadfence();  // acquire side
    }
    __syncthreads();
}

// ---------------------------------------------------------------------------
// Fused: phase1 (row norms in registers + atomicMax scatter) | grid barrier |
// phase2 (gather + combine + write out).
// One thread per (e,h) row per iteration; rows strided by NTHREADS so all
// accesses stay coalesced.
// ---------------------------------------------------------------------------
__global__ __launch_bounds__(TPB, 4) void lip_fused(
    const float* __restrict__ x, const float* __restrict__ att_l,
    const float* __restrict__ att_r, const float* __restrict__ alpha,
    const int* __restrict__ index, float* __restrict__ out,
    unsigned* __restrict__ seg, unsigned* __restrict__ bar, int rows)
{
    __shared__ float s_natt[H_DIM];
    int t = threadIdx.x;
    if (t < H_DIM) {
        float s = 0.f;
        #pragma unroll
        for (int c = 0; c < C_DIM; ++c) {
            float l = att_l[t * C_DIM + c];
            float r = att_r[t * C_DIM + c];
            s += l * l + r * r;
        }
        s_natt[t] = ATT_NORM_F * sqrtf(s);
    }
    // (visibility of s_natt is ordered by the __syncthreads inside the barrier)

    const int tid = blockIdx.x * TPB + t;
    const float4* x4 = (const float4*)x;
    float nrm[ITERS];

    #pragma unroll
    for (int i = 0; i < ITERS; ++i) {
        int r = tid + i * NTHREADS;
        nrm[i] = 0.f;
        if (r < rows) {
            float s = 0.f;
            #pragma unroll
            for (int q = 0; q < 4; ++q) {
                float4 v = x4[(size_t)r * 4 + q];
                s += v.x * v.x + v.y * v.y + v.z * v.z + v.w * v.w;
            }
            nrm[i] = s;
            int e = r >> 3;
            int h = r & 7;
            // s >= 0: float bits are monotone under unsigned max
            atomicMax(&seg[(size_t)index[e] * H_DIM + h], __float_as_uint(s));
        }
    }

    grid_barrier(bar, NBLK);

    #pragma unroll
    for (int i = 0; i < ITERS; ++i) {
        int r = tid + i * NTHREADS;
        if (r < rows) {
            int e = r >> 3;
            int h = r & 7;
            // agent-scope load: bypass the (non-coherent) per-XCD L2s
            unsigned sgb = __hip_atomic_load(
                &seg[(size_t)index[e] * H_DIM + h],
                __ATOMIC_RELAXED, __HIP_MEMORY_SCOPE_AGENT);
            out[r] = alpha[r] /
                     (s_natt[h] * sqrtf(__uint_as_float(sgb) + nrm[i]) + EPSF);
        }
    }
}

// ---------------------------------------------------------------------------
// Fallback (should not trigger: ws is ~2 GB): original 3-dispatch pipeline.
// ---------------------------------------------------------------------------
__global__ __launch_bounds__(256) void lip_pass1(
    const float* __restrict__ x, const int* __restrict__ index,
    unsigned int* __restrict__ seg, int rows)
{
    int tid = blockIdx.x * blockDim.x + threadIdx.x;
    int r = tid >> 2;
    int lane = tid & 3;
    if (r >= rows) return;
    const float4* x4 = (const float4*)x;
    float4 v = x4[(size_t)r * 4 + lane];
    float s = v.x * v.x + v.y * v.y + v.z * v.z + v.w * v.w;
    s += __shfl_xor(s, 1);
    s += __shfl_xor(s, 2);
    if (lane == 0) {
        int e = r >> 3, h = r & 7;
        atomicMax(&seg[(size_t)index[e] * H_DIM + h], __float_as_uint(s));
    }
}

__global__ __launch_bounds__(256) void lip_pass2_recompute(
    const float* __restrict__ x, const float* __restrict__ alpha,
    const int* __restrict__ index, const unsigned int* __restrict__ seg,
    const float* __restrict__ att_l, const float* __restrict__ att_r,
    float* __restrict__ out, int rows)
{
    __shared__ float s_natt[H_DIM];
    int t = threadIdx.x;
    if (t < H_DIM) {
        float s = 0.f;
        #pragma unroll
        for (int c = 0; c < C_DIM; ++c) {
            float l = att_l[t * C_DIM + c];
            float r = att_r[t * C_DIM + c];
            s += l * l + r * r;
        }
        s_natt[t] = ATT_NORM_F * sqrtf(s);
    }
    __syncthreads();
    int r = blockIdx.x * blockDim.x + t;
    if (r >= rows) return;
    const float4* x4 = (const float4*)x;
    float s = 0.f;
    #pragma unroll
    for (int q = 0; q < 4; ++q) {
        float4 v = x4[(size_t)r * 4 + q];
        s += v.x * v.x + v.y * v.y + v.z * v.z + v.w * v.w;
    }
    int e = r >> 3, h = r & 7;
    float sg = __uint_as_float(seg[(size_t)index[e] * H_DIM + h]);
    out[r] = alpha[r] / (s_natt[h] * sqrtf(sg + s) + EPSF);
}

extern "C" void kernel_launch(void* const* d_in, const int* in_sizes, int n_in,
                              void* d_out, int out_size, void* d_ws, size_t ws_size,
                              hipStream_t stream) {
    const float* x     = (const float*)d_in[0];
    const float* att_l = (const float*)d_in[1];
    const float* att_r = (const float*)d_in[2];
    const float* alpha = (const float*)d_in[3];
    const int*   index = (const int*)d_in[4];

    const int E    = in_sizes[4];
    const int rows = E * H_DIM;

    const int seg_words = N_NODES * H_DIM;        // 800000
    const int zero_words = seg_words + 2;         // + barrier count/gen
    unsigned* seg = (unsigned*)d_ws;
    unsigned* bar = seg + seg_words;

    if (ws_size >= (size_t)zero_words * 4) {
        lip_zero<<<(zero_words + 255) / 256, 256, 0, stream>>>(seg, zero_words);
        lip_fused<<<NBLK, TPB, 0, stream>>>(
            x, att_l, att_r, alpha, index, (float*)d_out, seg, bar, rows);
    } else {
        // minimal fallback (recompute path), needs only the seg table
        lip_zero<<<(seg_words + 255) / 256, 256, 0, stream>>>(seg, seg_words);
        int t1 = rows * 4;
        lip_pass1<<<(t1 + 255) / 256, 256, 0, stream>>>(x, index, seg, rows);
        lip_pass2_recompute<<<(rows + 255) / 256, 256, 0, stream>>>(
            x, alpha, index, seg, att_l, att_r, (float*)d_out, rows);
    }
}

// Round 3
// 154.605 us; speedup vs baseline: 3.3238x; 3.3238x over previous
//
#include <hip/hip_runtime.h>
#include <math.h>

#define EPSF 1e-12f
#define ATT_NORM_F 4.0f
#define H_DIM 8
#define C_DIM 16
#define N_NODES 100000

// ---------------------------------------------------------------------------
// Zero the seg table: one word per thread, massively parallel (the rocclr
// fillBufferAligned ran at ~10 GB/s in the R1 profile — pathological).
// ---------------------------------------------------------------------------
__global__ __launch_bounds__(256) void lip_zero(unsigned* __restrict__ p, int n)
{
    int i = blockIdx.x * 256 + threadIdx.x;
    if (i < n) p[i] = 0u;
}

// ---------------------------------------------------------------------------
// Pass 1: norm_x[e,h] = sum_c x[e,h,c]^2 ; seg[idx[e],h] = max(...)
// 4 lanes cooperate on one (e,h) row (16 floats = 4 x float4), fully
// coalesced: a 64-lane wave covers 16 rows = 1 KB contiguous per load.
// ---------------------------------------------------------------------------
__global__ __launch_bounds__(256) void lip_pass1(
    const float* __restrict__ x, const int* __restrict__ index,
    float* __restrict__ norm_x, unsigned int* __restrict__ seg, int rows)
{
    int tid = blockIdx.x * blockDim.x + threadIdx.x;
    int r = tid >> 2;            // (e,h) row id
    int lane = tid & 3;
    if (r >= rows) return;

    const float4* x4 = (const float4*)x;
    float4 v = x4[(size_t)r * 4 + lane];
    float s = v.x * v.x + v.y * v.y + v.z * v.z + v.w * v.w;
    // reduce across the 4-lane group (groups are contiguous within the wave)
    s += __shfl_xor(s, 1);
    s += __shfl_xor(s, 2);

    if (lane == 0) {
        norm_x[r] = s;
        int e = r >> 3;          // r / H_DIM
        int h = r & 7;           // r % H_DIM
        // s >= 0, so float bit pattern is monotone under unsigned compare
        atomicMax(&seg[(size_t)index[e] * H_DIM + h], __float_as_uint(s));
    }
}

// ---------------------------------------------------------------------------
// Pass 2: out[e,h] = alpha[e,h] / (natt[h] * sqrt(seg[idx[e],h] + norm_x[e,h]) + eps)
// One thread handles 4 consecutive heads (float4 everywhere). seg gathers are
// 16 B aligned from a 3.2 MB table that fits in each XCD's 4 MB L2.
// Cross-XCD visibility of pass-1 atomics is guaranteed by the dispatch
// boundary (runtime cache maintenance between kernels on one stream).
// ---------------------------------------------------------------------------
__global__ __launch_bounds__(256) void lip_pass2(
    const float* __restrict__ norm_x, const float* __restrict__ alpha,
    const int* __restrict__ index, const unsigned int* __restrict__ seg,
    const float* __restrict__ att_l, const float* __restrict__ att_r,
    float* __restrict__ out, int total)   // total = E*2
{
    __shared__ float s_natt[H_DIM];
    int t = threadIdx.x;
    if (t < H_DIM) {
        float s = 0.f;
        #pragma unroll
        for (int c = 0; c < C_DIM; ++c) {
            float l = att_l[t * C_DIM + c];
            float r = att_r[t * C_DIM + c];
            s += l * l + r * r;
        }
        s_natt[t] = ATT_NORM_F * sqrtf(s);
    }
    __syncthreads();

    int tid = blockIdx.x * blockDim.x + t;
    if (tid >= total) return;

    int e    = tid >> 1;
    int half = tid & 1;
    int idx  = index[e];

    const float4* nx4 = (const float4*)norm_x;
    const float4* al4 = (const float4*)alpha;
    const float4* sg4 = (const float4*)seg;   // bits are non-negative floats

    float4 nx = nx4[tid];
    float4 al = al4[tid];
    float4 sg = sg4[(size_t)idx * 2 + half];

    int h0 = half * 4;
    float4 o;
    o.x = al.x / (s_natt[h0 + 0] * sqrtf(sg.x + nx.x) + EPSF);
    o.y = al.y / (s_natt[h0 + 1] * sqrtf(sg.y + nx.y) + EPSF);
    o.z = al.z / (s_natt[h0 + 2] * sqrtf(sg.z + nx.z) + EPSF);
    o.w = al.w / (s_natt[h0 + 3] * sqrtf(sg.w + nx.w) + EPSF);
    ((float4*)out)[tid] = o;
}

// ---------------------------------------------------------------------------
// Fallback pass 2 (no norm_x buffer): recompute norm from x, scalar path.
// ---------------------------------------------------------------------------
__global__ __launch_bounds__(256) void lip_pass2_recompute(
    const float* __restrict__ x, const float* __restrict__ alpha,
    const int* __restrict__ index, const unsigned int* __restrict__ seg,
    const float* __restrict__ att_l, const float* __restrict__ att_r,
    float* __restrict__ out, int rows)
{
    __shared__ float s_natt[H_DIM];
    int t = threadIdx.x;
    if (t < H_DIM) {
        float s = 0.f;
        #pragma unroll
        for (int c = 0; c < C_DIM; ++c) {
            float l = att_l[t * C_DIM + c];
            float r = att_r[t * C_DIM + c];
            s += l * l + r * r;
        }
        s_natt[t] = ATT_NORM_F * sqrtf(s);
    }
    __syncthreads();

    int r = blockIdx.x * blockDim.x + t;
    if (r >= rows) return;

    const float4* x4 = (const float4*)x;
    float s = 0.f;
    #pragma unroll
    for (int q = 0; q < 4; ++q) {
        float4 v = x4[(size_t)r * 4 + q];
        s += v.x * v.x + v.y * v.y + v.z * v.z + v.w * v.w;
    }
    int e = r >> 3;
    int h = r & 7;
    float sg = __uint_as_float(seg[(size_t)index[e] * H_DIM + h]);
    out[r] = alpha[r] / (s_natt[h] * sqrtf(sg + s) + EPSF);
}

extern "C" void kernel_launch(void* const* d_in, const int* in_sizes, int n_in,
                              void* d_out, int out_size, void* d_ws, size_t ws_size,
                              hipStream_t stream) {
    const float* x     = (const float*)d_in[0];
    const float* att_l = (const float*)d_in[1];
    const float* att_r = (const float*)d_in[2];
    const float* alpha = (const float*)d_in[3];
    const int*   index = (const int*)d_in[4];

    const int E    = in_sizes[4];
    const int rows = E * H_DIM;

    const int seg_words = N_NODES * H_DIM;        // 800000 = 3.2 MB
    size_t seg_pad = ((size_t)seg_words * 4 + 255) / 256 * 256;
    size_t need    = seg_pad + (size_t)rows * sizeof(float);

    unsigned* seg = (unsigned*)d_ws;
    lip_zero<<<(seg_words + 255) / 256, 256, 0, stream>>>(seg, seg_words);

    if (ws_size >= need) {
        float* norm_x = (float*)((char*)d_ws + seg_pad);
        int t1 = rows * 4;
        lip_pass1<<<(t1 + 255) / 256, 256, 0, stream>>>(x, index, norm_x, seg, rows);
        int t2 = E * 2;
        lip_pass2<<<(t2 + 255) / 256, 256, 0, stream>>>(
            norm_x, alpha, index, seg, att_l, att_r, (float*)d_out, t2);
    } else {
        int t1 = rows * 4;
        lip_pass1<<<(t1 + 255) / 256, 256, 0, stream>>>(x, index, (float*)d_out, seg, rows);
        lip_pass2_recompute<<<(rows + 255) / 256, 256, 0, stream>>>(
            x, alpha, index, seg, att_l, att_r, (float*)d_out, rows);
    }
}

// Round 4
// 140.971 us; speedup vs baseline: 3.6453x; 1.0967x over previous
//
#include <hip/hip_runtime.h>
#include <math.h>

#define EPSF 1e-12f
#define ATT_NORM_F 4.0f
#define H_DIM 8
#define C_DIM 16
#define N_NODES 100000

typedef float v4f __attribute__((ext_vector_type(4)));

// ---------------------------------------------------------------------------
// Zero the seg table.
// ---------------------------------------------------------------------------
__global__ __launch_bounds__(256) void lip_zero(unsigned* __restrict__ p, int n)
{
    int i = blockIdx.x * 256 + threadIdx.x;
    if (i < n) p[i] = 0u;
}

// ---------------------------------------------------------------------------
// Pass 1 (grid-stride): norm_x[r] = sum_c x[r,c]^2 ; atomicMax into seg.
// 4 lanes per (e,h) row; 2048 blocks, each thread ~61 independent 16B loads
// (unroll 4 -> MLP). x is streamed non-temporally (no reuse, keep L2 for seg).
// ---------------------------------------------------------------------------
__global__ __launch_bounds__(256) void lip_pass1(
    const float* __restrict__ x, const int* __restrict__ index,
    float* __restrict__ norm_x, unsigned int* __restrict__ seg, int total /*rows*4*/)
{
    const int stride = gridDim.x * 256;
    const int s0 = blockIdx.x * 256 + threadIdx.x;
    const int lane = s0 & 3;                 // stride % 4 == 0 -> constant
    const v4f* x4 = (const v4f*)x;

    #pragma unroll 4
    for (int s = s0; s < total; s += stride) {
        v4f v = __builtin_nontemporal_load(&x4[s]);
        float sum = v.x * v.x + v.y * v.y + v.z * v.z + v.w * v.w;
        // total is a multiple of 4 and quads are aligned: all 4 lanes of a
        // quad are uniformly in- or out-of-range.
        sum += __shfl_xor(sum, 1);
        sum += __shfl_xor(sum, 2);
        if (lane == 0) {
            int r = s >> 2;
            __builtin_nontemporal_store(sum, &norm_x[r]);
            int e = r >> 3;
            int h = r & 7;
            // sum >= 0: float bits monotone under unsigned max
            atomicMax(&seg[(size_t)index[e] * H_DIM + h], __float_as_uint(sum));
        }
    }
}

// ---------------------------------------------------------------------------
// Pass 2 (grid-stride): out = alpha / (natt * sqrt(seg[idx] + norm_x) + eps)
// One thread per 4 heads (float4). seg/index stay cached; streams are nt.
// ---------------------------------------------------------------------------
__global__ __launch_bounds__(256) void lip_pass2(
    const float* __restrict__ norm_x, const float* __restrict__ alpha,
    const int* __restrict__ index, const unsigned int* __restrict__ seg,
    const float* __restrict__ att_l, const float* __restrict__ att_r,
    float* __restrict__ out, int total)   // total = E*2
{
    __shared__ float s_natt[H_DIM];
    int t = threadIdx.x;
    if (t < H_DIM) {
        float s = 0.f;
        #pragma unroll
        for (int c = 0; c < C_DIM; ++c) {
            float l = att_l[t * C_DIM + c];
            float r = att_r[t * C_DIM + c];
            s += l * l + r * r;
        }
        s_natt[t] = ATT_NORM_F * sqrtf(s);
    }
    __syncthreads();

    const int stride = gridDim.x * 256;
    const v4f* nx4 = (const v4f*)norm_x;
    const v4f* al4 = (const v4f*)alpha;
    const v4f* sg4 = (const v4f*)seg;       // bits are non-negative floats
    v4f* out4 = (v4f*)out;

    #pragma unroll 2
    for (int tid = blockIdx.x * 256 + t; tid < total; tid += stride) {
        int e    = tid >> 1;
        int half = tid & 1;
        int idx  = index[e];

        v4f nx = __builtin_nontemporal_load(&nx4[tid]);
        v4f al = __builtin_nontemporal_load(&al4[tid]);
        v4f sg = sg4[(size_t)idx * 2 + half];    // cached gather

        int h0 = half * 4;
        v4f o;
        o.x = al.x / (s_natt[h0 + 0] * sqrtf(sg.x + nx.x) + EPSF);
        o.y = al.y / (s_natt[h0 + 1] * sqrtf(sg.y + nx.y) + EPSF);
        o.z = al.z / (s_natt[h0 + 2] * sqrtf(sg.z + nx.z) + EPSF);
        o.w = al.w / (s_natt[h0 + 3] * sqrtf(sg.w + nx.w) + EPSF);
        __builtin_nontemporal_store(o, &out4[tid]);
    }
}

// ---------------------------------------------------------------------------
// Fallback pass 2 (no norm_x buffer): recompute norm from x, scalar path.
// ---------------------------------------------------------------------------
__global__ __launch_bounds__(256) void lip_pass2_recompute(
    const float* __restrict__ x, const float* __restrict__ alpha,
    const int* __restrict__ index, const unsigned int* __restrict__ seg,
    const float* __restrict__ att_l, const float* __restrict__ att_r,
    float* __restrict__ out, int rows)
{
    __shared__ float s_natt[H_DIM];
    int t = threadIdx.x;
    if (t < H_DIM) {
        float s = 0.f;
        #pragma unroll
        for (int c = 0; c < C_DIM; ++c) {
            float l = att_l[t * C_DIM + c];
            float r = att_r[t * C_DIM + c];
            s += l * l + r * r;
        }
        s_natt[t] = ATT_NORM_F * sqrtf(s);
    }
    __syncthreads();

    int r = blockIdx.x * blockDim.x + t;
    if (r >= rows) return;

    const float4* x4 = (const float4*)x;
    float s = 0.f;
    #pragma unroll
    for (int q = 0; q < 4; ++q) {
        float4 v = x4[(size_t)r * 4 + q];
        s += v.x * v.x + v.y * v.y + v.z * v.z + v.w * v.w;
    }
    int e = r >> 3;
    int h = r & 7;
    float sg = __uint_as_float(seg[(size_t)index[e] * H_DIM + h]);
    out[r] = alpha[r] / (s_natt[h] * sqrtf(sg + s) + EPSF);
}

extern "C" void kernel_launch(void* const* d_in, const int* in_sizes, int n_in,
                              void* d_out, int out_size, void* d_ws, size_t ws_size,
                              hipStream_t stream) {
    const float* x     = (const float*)d_in[0];
    const float* att_l = (const float*)d_in[1];
    const float* att_r = (const float*)d_in[2];
    const float* alpha = (const float*)d_in[3];
    const int*   index = (const int*)d_in[4];

    const int E    = in_sizes[4];
    const int rows = E * H_DIM;

    const int seg_words = N_NODES * H_DIM;        // 800000 = 3.2 MB
    size_t seg_pad = ((size_t)seg_words * 4 + 255) / 256 * 256;
    size_t need    = seg_pad + (size_t)rows * sizeof(float);

    unsigned* seg = (unsigned*)d_ws;
    lip_zero<<<(seg_words + 255) / 256, 256, 0, stream>>>(seg, seg_words);

    if (ws_size >= need) {
        float* norm_x = (float*)((char*)d_ws + seg_pad);
        lip_pass1<<<2048, 256, 0, stream>>>(x, index, norm_x, seg, rows * 4);
        lip_pass2<<<2048, 256, 0, stream>>>(
            norm_x, alpha, index, seg, att_l, att_r, (float*)d_out, E * 2);
    } else {
        lip_pass1<<<2048, 256, 0, stream>>>(x, index, (float*)d_out, seg, rows * 4);
        lip_pass2_recompute<<<(rows + 255) / 256, 256, 0, stream>>>(
            x, alpha, index, seg, att_l, att_r, (float*)d_out, rows);
    }
}